// Round 3
// baseline (153.232 us; speedup 1.0000x reference)
//
#include <hip/hip_runtime.h>

typedef unsigned short u16;
typedef unsigned char u8;
typedef unsigned int u32;
typedef __bf16 bf16x8 __attribute__((ext_vector_type(8)));
typedef float  f32x16 __attribute__((ext_vector_type(16)));
typedef int    i32x4  __attribute__((ext_vector_type(4)));
typedef int    i32x16 __attribute__((ext_vector_type(16)));

#define NB 4
#define NN 4096
#define ND 256

#define QPV (127.0f / 4.5f)        // pv quant scale
#define DPV (4.5f / 16129.0f)      // O dequant
#define QST (127.0f / 4.6f)        // state quant scale
#define DST (4.6f / 16129.0f)      // ds dequant
#define MAGIC 12582912.0f          // 1.5*2^23: fma(x,s,MAGIC) -> low byte = int8(x*s) rne

__device__ __forceinline__ u16 f2bf(float x) { return __builtin_bit_cast(u16, (__bf16)x); }
__device__ __forceinline__ u32 fbits(float x) { return __builtin_bit_cast(u32, x); }

// pack low bytes of 4 magic-biased floats into one dword (3 x v_perm_b32)
__device__ __forceinline__ u32 packlow4(float a, float b, float c, float d) {
    u32 p = __builtin_amdgcn_perm(fbits(b), fbits(a), 0x00000400u);
    u32 q = __builtin_amdgcn_perm(fbits(d), fbits(c), 0x00000400u);
    return __builtin_amdgcn_perm(q, p, 0x05040100u);
}

typedef __attribute__((address_space(1))) const u32 gas_u32;
typedef __attribute__((address_space(3))) u32 las_u32;
__device__ __forceinline__ void async_ld16(void* lds, const void* g) {
    __builtin_amdgcn_global_load_lds((gas_u32*)g, (las_u32*)lds, 16, 0, 0);
}

// ws layout:
//  kq8 : [b*128+strip][s8][lane64][16B]    i8 val frags (A/B operand), 4 MB
//  vp8 : [b*128+strip][slot9][lane64][16B] i8 frags: slot0..7 = pv^T, slot8 = state bcast, 4.5 MB
//  kq  : [b*128+strip][s16][lane64][8]     bf16 val frags (k_pv input), 8 MB
//  wv  : [es8][s16][lane64][8]             bf16 Wv^T frags, 128 KB
//  srow: [b*4096+n] f32 = rowmax/127, 64 KB

__global__ __launch_bounds__(256) void k_prep(const float* __restrict__ val,
                                              const float* __restrict__ state,
                                              const float* __restrict__ Wv,
                                              u16* __restrict__ kq, u8* __restrict__ kq8,
                                              float* __restrict__ srow,
                                              u8* __restrict__ vp8, u16* __restrict__ wv) {
    int tid = threadIdx.x;
    int bid = blockIdx.x;
    if (bid < 512) {
        __shared__ float t[32 * 257];
        __shared__ float rmax[32];
        const float* src = val + (size_t)bid * 32 * 256;
        #pragma unroll
        for (int k = 0; k < 8; k++) {
            int idx = tid + k * 256;
            int row = idx >> 6, c4 = idx & 63;
            float4 v = *(const float4*)(src + row * 256 + c4 * 4);
            float* p = t + row * 257 + c4 * 4;
            p[0] = v.x; p[1] = v.y; p[2] = v.z; p[3] = v.w;
        }
        __syncthreads();
        {
            int row = tid >> 3, seg = tid & 7;
            float m = 0.0f;
            #pragma unroll
            for (int i = 0; i < 32; i++) m = fmaxf(m, fabsf(t[row * 257 + seg + i * 8]));
            m = fmaxf(m, __shfl_down(m, 4));
            m = fmaxf(m, __shfl_down(m, 2));
            m = fmaxf(m, __shfl_down(m, 1));
            if (seg == 0) {
                m = fmaxf(m, 1e-20f);
                rmax[row] = m;
                srow[bid * 32 + row] = m * (1.0f / 127.0f);
            }
        }
        __syncthreads();
        u16* dst = kq + (size_t)bid * 16 * 512;
        #pragma unroll
        for (int k = 0; k < 4; k++) {
            int flat = tid + k * 256;
            int s = flat >> 6, l = flat & 63;
            int l31 = l & 31, h = l >> 5;
            const float* p = t + l31 * 257 + s * 16 + h * 8;
            union { u16 o[8]; uint4 q; } u;
            #pragma unroll
            for (int j = 0; j < 8; j++) u.o[j] = f2bf(p[j]);
            *(uint4*)(dst + (size_t)flat * 8) = u.q;
        }
        // i8 frags, per-row scale; |val|<=rmax so no clamp needed
        u8* dst8 = kq8 + (size_t)bid * 8192;
        #pragma unroll
        for (int k = 0; k < 2; k++) {
            int flat = tid + k * 256;
            int s = flat >> 6, l = flat & 63;
            int l31 = l & 31, h = l >> 5;
            float r127 = 127.0f / rmax[l31];
            const float* p = t + l31 * 257 + s * 32 + h * 16;
            u32 d[4];
            #pragma unroll
            for (int g = 0; g < 4; g++)
                d[g] = packlow4(fmaf(p[4 * g + 0], r127, MAGIC), fmaf(p[4 * g + 1], r127, MAGIC),
                                fmaf(p[4 * g + 2], r127, MAGIC), fmaf(p[4 * g + 3], r127, MAGIC));
            *(uint4*)(dst8 + (size_t)flat * 16) = make_uint4(d[0], d[1], d[2], d[3]);
        }
    } else if (bid < 516) {
        int b = bid - 512;
        __shared__ u8 qs[4096];
        #pragma unroll
        for (int k = 0; k < 16; k++) {
            int i = tid + k * 256;
            float x = fminf(fmaxf(state[b * 4096 + i] * QST, -127.0f), 127.0f);
            qs[i] = (u8)(fbits(x + MAGIC) & 255);
        }
        __syncthreads();
        #pragma unroll
        for (int k = 0; k < 32; k++) {
            int chunk = tid + k * 256;
            int strip = chunk >> 6, lane = chunk & 63, h = (lane >> 5) & 1;
            i32x4 v = *(const i32x4*)(qs + strip * 32 + h * 16);
            *(i32x4*)(vp8 + ((size_t)((b * 128 + strip) * 9 + 8)) * 1024 + (chunk & 63) * 16) = v;
        }
    } else {
        __shared__ u16 t2[256 * 33];
        int es = bid - 516, e0 = es * 32;
        #pragma unroll
        for (int k = 0; k < 8; k++) {
            int idx = tid + k * 256;
            int row = idx >> 3, c4 = idx & 7;
            float4 v = *(const float4*)(Wv + row * 256 + e0 + c4 * 4);
            u16* p = t2 + row * 33 + c4 * 4;
            p[0] = f2bf(v.x); p[1] = f2bf(v.y); p[2] = f2bf(v.z); p[3] = f2bf(v.w);
        }
        __syncthreads();
        u16* dst = wv + (size_t)es * 16 * 512;
        #pragma unroll
        for (int k = 0; k < 4; k++) {
            int flat = tid + k * 256;
            int s = flat >> 6, l = flat & 63;
            int l31 = l & 31, h = l >> 5;
            union { u16 o[8]; uint4 q; } u;
            #pragma unroll
            for (int j = 0; j < 8; j++) u.o[j] = t2[(s * 16 + h * 8 + j) * 33 + l31];
            *(uint4*)(dst + (size_t)flat * 8) = u.q;
        }
    }
}

// ---- pv^T = Wv^T x val^T (bf16 MFMA) -> i8 B-operand frags ----
// block = (bb, qb, qt-pair); wave = es-pair {w, w+4} with 2x2 MFMA reuse.
__global__ __launch_bounds__(256) void k_pv(const u16* __restrict__ kq, const u16* __restrict__ wv,
                                            u8* __restrict__ vp8) {
    __shared__ u8 tp[4][32 * 48];
    int tid = threadIdx.x;
    int w = tid >> 6, lane = tid & 63;
    int l31 = lane & 31, h = lane >> 5;
    int bid = blockIdx.x;                 // [0,256)
    int bb = bid >> 6;                    // [0,4)
    int qb = (bid >> 1) & 31;             // [0,32)
    int qh = bid & 1;                     // qt-pair select
    const u16* wv0 = wv + (size_t)(w * 16) * 512 + lane * 8;
    const u16* wv1 = wv + (size_t)((w + 4) * 16) * 512 + lane * 8;
    const u16* kqb = kq + ((size_t)((bb * 128 + qb * 4 + qh * 2) * 16)) * 512 + lane * 8;
    f32x16 acc[2][2] = {};
    for (int s = 0; s < 16; s++) {
        bf16x8 a0 = *(const bf16x8*)(wv0 + s * 512);
        bf16x8 a1 = *(const bf16x8*)(wv1 + s * 512);
        bf16x8 b0 = *(const bf16x8*)(kqb + (size_t)s * 512);
        bf16x8 b1 = *(const bf16x8*)(kqb + (size_t)(16 + s) * 512);
        acc[0][0] = __builtin_amdgcn_mfma_f32_32x32x16_bf16(a0, b0, acc[0][0], 0, 0, 0);
        acc[0][1] = __builtin_amdgcn_mfma_f32_32x32x16_bf16(a0, b1, acc[0][1], 0, 0, 0);
        acc[1][0] = __builtin_amdgcn_mfma_f32_32x32x16_bf16(a1, b0, acc[1][0], 0, 0, 0);
        acc[1][1] = __builtin_amdgcn_mfma_f32_32x32x16_bf16(a1, b1, acc[1][1], 0, 0, 0);
    }
    u8* myp = tp[w];
    #pragma unroll
    for (int e = 0; e < 2; e++) {
        #pragma unroll
        for (int j = 0; j < 2; j++) {
            int es = w + 4 * e;
            int qt = qh * 2 + j;
            #pragma unroll
            for (int r = 0; r < 16; r++) {
                int erow = (r & 3) + 8 * (r >> 2) + 4 * h;
                float x = fminf(fmaxf(acc[e][j][r] * QPV, -127.0f), 127.0f);
                myp[erow * 48 + l31] = (u8)(fbits(x + MAGIC) & 255);
            }
            i32x4 v = *(const i32x4*)(myp + l31 * 48 + h * 16);
            *(i32x4*)(vp8 + ((size_t)((bb * 128 + qb * 4 + qt) * 9 + es)) * 1024 + lane * 16) = v;
        }
    }
}

// ---- main (R3): et-split + DMA-staged V (dbuf, global_load_lds) + reg-prefetch K ----
// wave w: computes S^T for m-strip (mt*4+w), shares P via pbuf; owns output cols
// et in {2w, 2w+1}. V slots staged to LDS by DMA (no VGPR cost, full-iter latency
// window); race-free because __syncthreads drains vmcnt(0) before s_barrier, so
// every wave's DMA has landed before the barrier preceding the cross-wave PV reads.
__global__ __launch_bounds__(256, 2) void k_main(const u8* __restrict__ kq8,
                                                 const u8* __restrict__ vp8,
                                                 const float* __restrict__ srow,
                                                 float* __restrict__ ds_out,
                                                 float* __restrict__ dval_out) {
    __shared__ u8 vstage[2][4][8192];          // [buf][strip][slot0..7][lane][16B], 64 KB
    __shared__ i32x4 pbuf[2][4][64];           // P frag exchange, double-buffered (8 KB)
    __shared__ int dsqi[4][32];

    int tid = threadIdx.x;
    int w = tid >> 6, lane = tid & 63;
    int l31 = lane & 31, h = lane >> 5;

    int id = blockIdx.x;                       // [0,512)
    int xcd = id & 7;
    int bb = xcd >> 1;
    int t7 = ((xcd & 1) << 6) | (id >> 3);     // q-strip [0,128)
    int q0 = t7 * 32;
    size_t bbase = (size_t)bb * 128;

    i32x4 qf[8];
    {
        const u8* qsrc = kq8 + (bbase + t7) * 8192 + lane * 16;
        #pragma unroll
        for (int s = 0; s < 8; s++) qf[s] = *(const i32x4*)(qsrc + (size_t)s * 1024);
    }
    float srq = srow[bb * 4096 + q0 + l31];

    i32x16 oacc[2] = {};
    i32x16 dsa = {};

    // prologue: DMA-stage V tile 0 (wave w stages strip w's slots 0..7)
    {
        u8* dst = vstage[0][w];
        const u8* src = vp8 + ((size_t)((bbase + w) * 9)) * 1024;
        #pragma unroll
        for (int k = 0; k < 8; k++)
            async_ld16(dst + (size_t)k * 1024 + lane * 16, src + (size_t)k * 1024 + lane * 16);
    }
    // prologue register loads (mt = 0)
    i32x4 kf[8], sf;
    float4 sg[4];
    {
        const u8* kb = kq8 + (bbase + w) * 8192 + lane * 16;
        #pragma unroll
        for (int s = 0; s < 8; s++) kf[s] = *(const i32x4*)(kb + (size_t)s * 1024);
        sf = *(const i32x4*)(vp8 + ((size_t)((bbase + w) * 9 + 8)) * 1024 + lane * 16);
        const float* srm = srow + bb * 4096 + w * 32;
        #pragma unroll
        for (int g = 0; g < 4; g++) sg[g] = *(const float4*)(srm + g * 8 + h * 4);
    }

    for (int mt = 0; mt < 32; mt++) {
        // ---- region A ----
        // S^T = K x Q^T, two independent chains
        i32x16 s0 = {}, s1 = {};
        __builtin_amdgcn_s_setprio(1);
        #pragma unroll
        for (int s = 0; s < 8; s += 2) {
            s0 = __builtin_amdgcn_mfma_i32_32x32x32_i8(kf[s], qf[s], s0, 0, 0, 0);
            s1 = __builtin_amdgcn_mfma_i32_32x32x32_i8(kf[s + 1], qf[s + 1], s1, 0, 0, 0);
        }
        __builtin_amdgcn_s_setprio(0);

        // prefetch next K frags / scales / state frag into registers (issued early;
        // vf no longer competes for VGPRs so these stay live across the barrier)
        i32x4 kf2[8], sf2;
        float4 sg2[4];
        if (mt + 1 < 32) {
            const u8* kb = kq8 + (bbase + (mt + 1) * 4 + w) * 8192 + lane * 16;
            #pragma unroll
            for (int s = 0; s < 8; s++) kf2[s] = *(const i32x4*)(kb + (size_t)s * 1024);
            sf2 = *(const i32x4*)(vp8 + ((size_t)((bbase + (mt + 1) * 4 + w) * 9 + 8)) * 1024 + lane * 16);
            const float* srm = srow + bb * 4096 + (mt + 1) * 128 + w * 32;
            #pragma unroll
            for (int g = 0; g < 4; g++) sg2[g] = *(const float4*)(srm + g * 8 + h * 4);
        }

        // dequant -> softsign -> magic-round to i8 (rne)
        float cf[16];
        #pragma unroll
        for (int r = 0; r < 16; r++) {
            float sm = ((const float*)&sg[r >> 2])[r & 3] * srq;
            float xs = (float)(s0[r] + s1[r]) * sm;
            float p = xs * __builtin_amdgcn_rcpf(1.0f + fabsf(xs));
            cf[r] = fmaf(p, 127.0f, MAGIC);
        }
        u32 w0 = packlow4(cf[0], cf[1], cf[2], cf[3]);
        u32 w1 = packlow4(cf[4], cf[5], cf[6], cf[7]);
        u32 w2 = packlow4(cf[8], cf[9], cf[10], cf[11]);
        u32 w3 = packlow4(cf[12], cf[13], cf[14], cf[15]);
        u32 x0 = (u32)__shfl_xor((int)w0, 32);
        u32 x1 = (u32)__shfl_xor((int)w1, 32);
        u32 x2 = (u32)__shfl_xor((int)w2, 32);
        u32 x3 = (u32)__shfl_xor((int)w3, 32);
        union { u32 wd[4]; i32x4 v; } pu;
        if (h == 0) { pu.wd[0] = w0; pu.wd[1] = x0; pu.wd[2] = w1; pu.wd[3] = x1; }
        else        { pu.wd[0] = x2; pu.wd[1] = w2; pu.wd[2] = x3; pu.wd[3] = w3; }
        i32x4 pf = pu.v;

        // ds partial for this wave's strip
        dsa = __builtin_amdgcn_mfma_i32_32x32x32_i8(pf, sf, dsa, 0, 0, 0);

        pbuf[mt & 1][w][lane] = pf;

        // barrier: compiler emits s_waitcnt vmcnt(0) lgkmcnt(0) before s_barrier ->
        // publishes pbuf AND guarantees every wave's V-stage DMA for this tile landed.
        __syncthreads();

        // ---- region B ----
        // DMA-stage next V tile into the other buffer (last read of that buffer was
        // before the PREVIOUS barrier -> no WAR race). Full-iteration latency window.
        if (mt + 1 < 32) {
            u8* dst = vstage[(mt + 1) & 1][w];
            const u8* src = vp8 + ((size_t)((bbase + (mt + 1) * 4 + w) * 9)) * 1024;
            #pragma unroll
            for (int k = 0; k < 8; k++)
                async_ld16(dst + (size_t)k * 1024 + lane * 16, src + (size_t)k * 1024 + lane * 16);
        }

        i32x4 pl[4];
        #pragma unroll
        for (int st = 0; st < 4; st++) pl[st] = pbuf[mt & 1][st][lane];

        // O(cols 2w,2w+1) += sum_st P(st) x Vt(st)  [V frags from LDS]
        const u8* vb = vstage[mt & 1][0];
        __builtin_amdgcn_s_setprio(1);
        #pragma unroll
        for (int st = 0; st < 4; st++) {
            i32x4 vf0 = *(const i32x4*)(vb + (size_t)st * 8192 + (2 * w) * 1024 + lane * 16);
            i32x4 vf1 = *(const i32x4*)(vb + (size_t)st * 8192 + (2 * w + 1) * 1024 + lane * 16);
            oacc[0] = __builtin_amdgcn_mfma_i32_32x32x32_i8(pl[st], vf0, oacc[0], 0, 0, 0);
            oacc[1] = __builtin_amdgcn_mfma_i32_32x32x32_i8(pl[st], vf1, oacc[1], 0, 0, 0);
        }
        __builtin_amdgcn_s_setprio(0);

        if (mt + 1 < 32) {
            #pragma unroll
            for (int s = 0; s < 8; s++) kf[s] = kf2[s];
            sf = sf2;
            #pragma unroll
            for (int g = 0; g < 4; g++) sg[g] = sg2[g];
        }
    }

    // ---- epilogue: each wave owns its output cols ----
    if (l31 == 0) {
        #pragma unroll
        for (int r = 0; r < 16; r++) dsqi[w][(r & 3) + 8 * (r >> 2) + 4 * h] = dsa[r];
    }
    #pragma unroll
    for (int e = 0; e < 2; e++) {
        #pragma unroll
        for (int r = 0; r < 16; r++) {
            int row = (r & 3) + 8 * (r >> 2) + 4 * h;
            dval_out[((size_t)(bb * 4096 + q0 + row)) * 256 + (2 * w + e) * 32 + l31] =
                (float)oacc[e][r] * DPV;
        }
    }
    __syncthreads();
    if (w == 0 && lane < 32) {
        int d = dsqi[0][lane] + dsqi[1][lane] + dsqi[2][lane] + dsqi[3][lane];
        ds_out[bb * 4096 + q0 + lane] = (float)d * DST;
    }
}

extern "C" void kernel_launch(void* const* d_in, const int* in_sizes, int n_in,
                              void* d_out, int out_size, void* d_ws, size_t ws_size,
                              hipStream_t stream) {
    const float* val   = (const float*)d_in[0];
    const float* state = (const float*)d_in[1];
    const float* Wv    = (const float*)d_in[2];

    float* ds_out   = (float*)d_out;
    float* dval_out = ds_out + NB * NN;

    u8*  kq8 = (u8*)d_ws;                                      // 4 MB
    u8*  vp8 = kq8 + (size_t)NB * NN * ND;                     // 4.5 MB
    u16* kq  = (u16*)(vp8 + (size_t)NB * 128 * 9216);          // 8 MB
    u16* wv  = kq + (size_t)NB * NN * ND;                      // 128 KB
    float* srow = (float*)(wv + 8 * 16 * 512);                 // 64 KB

    k_prep<<<524, 256, 0, stream>>>(val, state, Wv, kq, kq8, srow, vp8, wv);
    k_pv<<<256, 256, 0, stream>>>(kq, wv, vp8);
    k_main<<<512, 256, 0, stream>>>(kq8, vp8, srow, ds_out, dval_out);
}

// Round 4
// 136.913 us; speedup vs baseline: 1.1192x; 1.1192x over previous
//
#include <hip/hip_runtime.h>

typedef unsigned short u16;
typedef unsigned char u8;
typedef unsigned int u32;
typedef __bf16 bf16x8 __attribute__((ext_vector_type(8)));
typedef float  f32x16 __attribute__((ext_vector_type(16)));
typedef int    i32x4  __attribute__((ext_vector_type(4)));
typedef int    i32x16 __attribute__((ext_vector_type(16)));

#define NB 4
#define NN 4096
#define ND 256

#define QPV (127.0f / 4.5f)        // pv quant scale
#define DPV (4.5f / 16129.0f)      // O dequant
#define QST (127.0f / 4.6f)        // state quant scale
#define DST (4.6f / 16129.0f)      // ds dequant
#define MAGIC 12582912.0f          // 1.5*2^23: fma(x,s,MAGIC) -> low byte = int8(x*s) rne

__device__ __forceinline__ u16 f2bf(float x) { return __builtin_bit_cast(u16, (__bf16)x); }
__device__ __forceinline__ u32 fbits(float x) { return __builtin_bit_cast(u32, x); }

// pack low bytes of 4 magic-biased floats into one dword (3 x v_perm_b32)
__device__ __forceinline__ u32 packlow4(float a, float b, float c, float d) {
    u32 p = __builtin_amdgcn_perm(fbits(b), fbits(a), 0x00000400u);
    u32 q = __builtin_amdgcn_perm(fbits(d), fbits(c), 0x00000400u);
    return __builtin_amdgcn_perm(q, p, 0x05040100u);
}

// ws layout:
//  kq8 : [b*128+strip][s8][lane64][16B]    i8 val frags (A/B operand), 4 MB
//  vp8 : [b*128+strip][slot9][lane64][16B] i8 frags: slot0..7 = pv^T, slot8 = state bcast, 4.5 MB
//  wv  : [es8][s16][lane64][8]             bf16 Wv^T frags, 128 KB
//  srow: [b*4096+n] f32 = rowmax/127, 64 KB
// (kq bf16 workspace ELIMINATED: pv now fused into k_prep)

// ---- Wv frag prep (runs first, 8 blocks) ----
__global__ __launch_bounds__(256) void k_wv(const float* __restrict__ Wv, u16* __restrict__ wv) {
    __shared__ u16 t2[256 * 33];
    int tid = threadIdx.x;
    int es = blockIdx.x, e0 = es * 32;
    #pragma unroll
    for (int k = 0; k < 8; k++) {
        int idx = tid + k * 256;
        int row = idx >> 3, c4 = idx & 7;
        float4 v = *(const float4*)(Wv + row * 256 + e0 + c4 * 4);
        u16* p = t2 + row * 33 + c4 * 4;
        p[0] = f2bf(v.x); p[1] = f2bf(v.y); p[2] = f2bf(v.z); p[3] = f2bf(v.w);
    }
    __syncthreads();
    u16* dst = wv + (size_t)es * 16 * 512;
    #pragma unroll
    for (int k = 0; k < 4; k++) {
        int flat = tid + k * 256;
        int s = flat >> 6, l = flat & 63;
        int l31 = l & 31, h = l >> 5;
        union { u16 o[8]; uint4 q; } u;
        #pragma unroll
        for (int j = 0; j < 8; j++) u.o[j] = t2[(s * 16 + h * 8 + j) * 33 + l31];
        *(uint4*)(dst + (size_t)flat * 8) = u.q;
    }
}

// ---- prep: stage strip, rowmax, kq8 frags, FUSED pv -> vp8 frags ----
__global__ __launch_bounds__(256) void k_prep(const float* __restrict__ val,
                                              const float* __restrict__ state,
                                              const u16* __restrict__ wvf,
                                              u8* __restrict__ kq8,
                                              float* __restrict__ srow,
                                              u8* __restrict__ vp8) {
    int tid = threadIdx.x;
    int bid = blockIdx.x;
    if (bid < 512) {
        __shared__ float t[32 * 257];
        __shared__ float rmax[32];
        __shared__ u8 tp[4][32 * 48];
        const float* src = val + (size_t)bid * 32 * 256;
        #pragma unroll
        for (int k = 0; k < 8; k++) {
            int idx = tid + k * 256;
            int row = idx >> 6, c4 = idx & 63;
            float4 v = *(const float4*)(src + row * 256 + c4 * 4);
            float* p = t + row * 257 + c4 * 4;
            p[0] = v.x; p[1] = v.y; p[2] = v.z; p[3] = v.w;
        }
        __syncthreads();
        {
            int row = tid >> 3, seg = tid & 7;
            float m = 0.0f;
            #pragma unroll
            for (int i = 0; i < 32; i++) m = fmaxf(m, fabsf(t[row * 257 + seg + i * 8]));
            m = fmaxf(m, __shfl_down(m, 4));
            m = fmaxf(m, __shfl_down(m, 2));
            m = fmaxf(m, __shfl_down(m, 1));
            if (seg == 0) {
                m = fmaxf(m, 1e-20f);
                rmax[row] = m;
                srow[bid * 32 + row] = m * (1.0f / 127.0f);
            }
        }
        __syncthreads();
        // i8 frags, per-row scale; |val|<=rmax so no clamp needed
        u8* dst8 = kq8 + (size_t)bid * 8192;
        #pragma unroll
        for (int k = 0; k < 2; k++) {
            int flat = tid + k * 256;
            int s = flat >> 6, l = flat & 63;
            int l31 = l & 31, h = l >> 5;
            float r127 = 127.0f / rmax[l31];
            const float* p = t + l31 * 257 + s * 32 + h * 16;
            u32 d[4];
            #pragma unroll
            for (int g = 0; g < 4; g++)
                d[g] = packlow4(fmaf(p[4 * g + 0], r127, MAGIC), fmaf(p[4 * g + 1], r127, MAGIC),
                                fmaf(p[4 * g + 2], r127, MAGIC), fmaf(p[4 * g + 3], r127, MAGIC));
            *(uint4*)(dst8 + (size_t)flat * 16) = make_uint4(d[0], d[1], d[2], d[3]);
        }
        // ---- fused pv: pv[n,es] = sum_d val[n,d]*Wv[d,es] (A=val frags, B=Wv frags;
        // mirrored A/B lane layouts -> output row=n (r-mapped), col=es (lane&31)).
        // Produces BYTES IDENTICAL to the old k_pv path (same myp[es*48+n] addresses).
        {
            int w = tid >> 6, lane = tid & 63;
            int l31 = lane & 31, h = lane >> 5;
            const u16* wv0 = wvf + ((size_t)((w * 2 + 0) * 16)) * 512 + lane * 8;
            const u16* wv1 = wvf + ((size_t)((w * 2 + 1) * 16)) * 512 + lane * 8;
            f32x16 acc0 = {}, acc1 = {};
            for (int s = 0; s < 16; s++) {
                union { u16 o[8]; bf16x8 v; } ua;
                const float* p = t + l31 * 257 + s * 16 + h * 8;
                #pragma unroll
                for (int j = 0; j < 8; j++) ua.o[j] = f2bf(p[j]);
                bf16x8 b0 = *(const bf16x8*)(wv0 + (size_t)s * 512);
                bf16x8 b1 = *(const bf16x8*)(wv1 + (size_t)s * 512);
                acc0 = __builtin_amdgcn_mfma_f32_32x32x16_bf16(ua.v, b0, acc0, 0, 0, 0);
                acc1 = __builtin_amdgcn_mfma_f32_32x32x16_bf16(ua.v, b1, acc1, 0, 0, 0);
            }
            u8* myp = tp[w];
            #pragma unroll
            for (int r = 0; r < 16; r++) {
                int nrow = (r & 3) + 8 * (r >> 2) + 4 * h;
                float x = fminf(fmaxf(acc0[r] * QPV, -127.0f), 127.0f);
                myp[l31 * 48 + nrow] = (u8)(fbits(x + MAGIC) & 255);
            }
            i32x4 v0 = *(const i32x4*)(myp + l31 * 48 + h * 16);
            *(i32x4*)(vp8 + ((size_t)(bid * 9 + w * 2 + 0)) * 1024 + lane * 16) = v0;
            #pragma unroll
            for (int r = 0; r < 16; r++) {
                int nrow = (r & 3) + 8 * (r >> 2) + 4 * h;
                float x = fminf(fmaxf(acc1[r] * QPV, -127.0f), 127.0f);
                myp[l31 * 48 + nrow] = (u8)(fbits(x + MAGIC) & 255);
            }
            i32x4 v1 = *(const i32x4*)(myp + l31 * 48 + h * 16);
            *(i32x4*)(vp8 + ((size_t)(bid * 9 + w * 2 + 1)) * 1024 + lane * 16) = v1;
        }
    } else {
        int b = bid - 512;
        __shared__ u8 qs[4096];
        #pragma unroll
        for (int k = 0; k < 16; k++) {
            int i = tid + k * 256;
            float x = fminf(fmaxf(state[b * 4096 + i] * QST, -127.0f), 127.0f);
            qs[i] = (u8)(fbits(x + MAGIC) & 255);
        }
        __syncthreads();
        #pragma unroll
        for (int k = 0; k < 32; k++) {
            int chunk = tid + k * 256;
            int strip = chunk >> 6, lane = chunk & 63, h = (lane >> 5) & 1;
            i32x4 v = *(const i32x4*)(qs + strip * 32 + h * 16);
            *(i32x4*)(vp8 + ((size_t)((b * 128 + strip) * 9 + 8)) * 1024 + (chunk & 63) * 16) = v;
        }
    }
}

// ---- main (R2 structure, best measured 65.9us): et-split waves + LDS P-exchange,
// 1 barrier/iter; kf/vf/sf/sg single-buffer register prefetch for mt+1 ----
__global__ __launch_bounds__(256, 2) void k_main(const u8* __restrict__ kq8,
                                                 const u8* __restrict__ vp8,
                                                 const float* __restrict__ srow,
                                                 float* __restrict__ ds_out,
                                                 float* __restrict__ dval_out) {
    __shared__ i32x4 pbuf[2][4][64];           // P frag exchange, double-buffered (8 KB)
    __shared__ int dsqi[4][32];

    int tid = threadIdx.x;
    int w = tid >> 6, lane = tid & 63;
    int l31 = lane & 31, h = lane >> 5;

    int id = blockIdx.x;                       // [0,512)
    int xcd = id & 7;
    int bb = xcd >> 1;
    int t7 = ((xcd & 1) << 6) | (id >> 3);     // q-strip [0,128)
    int q0 = t7 * 32;
    size_t bbase = (size_t)bb * 128;

    i32x4 qf[8];
    {
        const u8* qsrc = kq8 + (bbase + t7) * 8192 + lane * 16;
        #pragma unroll
        for (int s = 0; s < 8; s++) qf[s] = *(const i32x4*)(qsrc + (size_t)s * 1024);
    }
    float srq = srow[bb * 4096 + q0 + l31];

    i32x16 oacc[2] = {};
    i32x16 dsa = {};

    // prologue loads (mt = 0)
    i32x4 kf[8], vf[4][2], sf;
    float4 sg[4];
    {
        const u8* kb = kq8 + (bbase + w) * 8192 + lane * 16;
        #pragma unroll
        for (int s = 0; s < 8; s++) kf[s] = *(const i32x4*)(kb + (size_t)s * 1024);
        #pragma unroll
        for (int st = 0; st < 4; st++)
            #pragma unroll
            for (int e = 0; e < 2; e++)
                vf[st][e] = *(const i32x4*)(vp8 + ((size_t)((bbase + st) * 9 + 2 * w + e)) * 1024 + lane * 16);
        sf = *(const i32x4*)(vp8 + ((size_t)((bbase + w) * 9 + 8)) * 1024 + lane * 16);
        const float* srm = srow + bb * 4096 + w * 32;
        #pragma unroll
        for (int g = 0; g < 4; g++) sg[g] = *(const float4*)(srm + g * 8 + h * 4);
    }

    for (int mt = 0; mt < 32; mt++) {
        // S^T = K x Q^T, two independent chains (halve serial MFMA dep latency)
        i32x16 s0 = {}, s1 = {};
        #pragma unroll
        for (int s = 0; s < 8; s += 2) {
            s0 = __builtin_amdgcn_mfma_i32_32x32x32_i8(kf[s], qf[s], s0, 0, 0, 0);
            s1 = __builtin_amdgcn_mfma_i32_32x32x32_i8(kf[s + 1], qf[s + 1], s1, 0, 0, 0);
        }
        // prefetch next kf (kf dead after QK issue; ~400cy of compute before next use)
        if (mt + 1 < 32) {
            const u8* kb = kq8 + (bbase + (mt + 1) * 4 + w) * 8192 + lane * 16;
            #pragma unroll
            for (int s = 0; s < 8; s++) kf[s] = *(const i32x4*)(kb + (size_t)s * 1024);
        }

        // dequant -> softsign -> magic-round to i8 (rne)
        float cf[16];
        #pragma unroll
        for (int r = 0; r < 16; r++) {
            float sm = ((const float*)&sg[r >> 2])[r & 3] * srq;
            float xs = (float)(s0[r] + s1[r]) * sm;
            float p = xs * __builtin_amdgcn_rcpf(1.0f + fabsf(xs));
            cf[r] = fmaf(p, 127.0f, MAGIC);
        }
        if (mt + 1 < 32) {
            const float* srm = srow + bb * 4096 + (mt + 1) * 128 + w * 32;
            #pragma unroll
            for (int g = 0; g < 4; g++) sg[g] = *(const float4*)(srm + g * 8 + h * 4);
        }
        u32 w0 = packlow4(cf[0], cf[1], cf[2], cf[3]);
        u32 w1 = packlow4(cf[4], cf[5], cf[6], cf[7]);
        u32 w2 = packlow4(cf[8], cf[9], cf[10], cf[11]);
        u32 w3 = packlow4(cf[12], cf[13], cf[14], cf[15]);
        u32 x0 = (u32)__shfl_xor((int)w0, 32);
        u32 x1 = (u32)__shfl_xor((int)w1, 32);
        u32 x2 = (u32)__shfl_xor((int)w2, 32);
        u32 x3 = (u32)__shfl_xor((int)w3, 32);
        union { u32 wd[4]; i32x4 v; } pu;
        if (h == 0) { pu.wd[0] = w0; pu.wd[1] = x0; pu.wd[2] = w1; pu.wd[3] = x1; }
        else        { pu.wd[0] = x2; pu.wd[1] = w2; pu.wd[2] = x3; pu.wd[3] = w3; }
        i32x4 pf = pu.v;

        // ds partial for this wave's strip (uses own pf, no exchange needed)
        dsa = __builtin_amdgcn_mfma_i32_32x32x32_i8(pf, sf, dsa, 0, 0, 0);
        if (mt + 1 < 32)
            sf = *(const i32x4*)(vp8 + ((size_t)((bbase + (mt + 1) * 4 + w) * 9 + 8)) * 1024 + lane * 16);

        // share P frags across waves (write(i) -> barrier(i) -> read(i); dbuf makes
        // one barrier/iter safe: writing buf[(i+2)&1] requires passing barrier(i+1),
        // which implies all waves completed their read(i))
        pbuf[mt & 1][w][lane] = pf;
        __syncthreads();
        i32x4 pl[4];
        #pragma unroll
        for (int st = 0; st < 4; st++) pl[st] = pbuf[mt & 1][st][lane];

        // O(cols 2w,2w+1) += sum_st P(st) x Vt(st)
        #pragma unroll
        for (int st = 0; st < 4; st++) {
            oacc[0] = __builtin_amdgcn_mfma_i32_32x32x32_i8(pl[st], vf[st][0], oacc[0], 0, 0, 0);
            oacc[1] = __builtin_amdgcn_mfma_i32_32x32x32_i8(pl[st], vf[st][1], oacc[1], 0, 0, 0);
        }
        // prefetch next vf (full iteration of latency window)
        if (mt + 1 < 32) {
            #pragma unroll
            for (int st = 0; st < 4; st++)
                #pragma unroll
                for (int e = 0; e < 2; e++)
                    vf[st][e] = *(const i32x4*)(vp8 + ((size_t)((bbase + (mt + 1) * 4 + st) * 9 + 2 * w + e)) * 1024 + lane * 16);
        }
    }

    // ---- epilogue: no cross-wave O reduction needed; each wave owns its cols ----
    if (l31 == 0) {
        #pragma unroll
        for (int r = 0; r < 16; r++) dsqi[w][(r & 3) + 8 * (r >> 2) + 4 * h] = dsa[r];
    }
    #pragma unroll
    for (int e = 0; e < 2; e++) {
        #pragma unroll
        for (int r = 0; r < 16; r++) {
            int row = (r & 3) + 8 * (r >> 2) + 4 * h;
            dval_out[((size_t)(bb * 4096 + q0 + row)) * 256 + (2 * w + e) * 32 + l31] =
                (float)oacc[e][r] * DPV;
        }
    }
    __syncthreads();
    if (w == 0 && lane < 32) {
        int d = dsqi[0][lane] + dsqi[1][lane] + dsqi[2][lane] + dsqi[3][lane];
        ds_out[bb * 4096 + q0 + lane] = (float)d * DST;
    }
}

extern "C" void kernel_launch(void* const* d_in, const int* in_sizes, int n_in,
                              void* d_out, int out_size, void* d_ws, size_t ws_size,
                              hipStream_t stream) {
    const float* val   = (const float*)d_in[0];
    const float* state = (const float*)d_in[1];
    const float* Wv    = (const float*)d_in[2];

    float* ds_out   = (float*)d_out;
    float* dval_out = ds_out + NB * NN;

    u8*  kq8 = (u8*)d_ws;                                      // 4 MB
    u8*  vp8 = kq8 + (size_t)NB * NN * ND;                     // 4.5 MB
    u16* wv  = (u16*)(vp8 + (size_t)NB * 128 * 9216);          // 128 KB
    float* srow = (float*)(wv + 8 * 16 * 512);                 // 64 KB

    k_wv<<<8, 256, 0, stream>>>(Wv, wv);
    k_prep<<<516, 256, 0, stream>>>(val, state, wv, kq8, srow, vp8);
    k_main<<<512, 256, 0, stream>>>(kq8, vp8, srow, ds_out, dval_out);
}